// Round 1
// baseline (82.341 us; speedup 1.0000x reference)
//
#include <hip/hip_runtime.h>
#include <hip/hip_bf16.h>

#define BB 16
#define SS 2048
#define DD 1024
#define HH 16
#define KK 31
#define HK 496

typedef float f32x4 __attribute__((ext_vector_type(4)));
typedef __bf16 bf16x8 __attribute__((ext_vector_type(8)));

__device__ __forceinline__ unsigned short f2bf(float x) {
  unsigned u = __float_as_uint(x);
  unsigned r = u + 0x7FFFu + ((u >> 16) & 1u);
  return (unsigned short)(r >> 16);
}

__device__ __forceinline__ void gll16(const void* g, void* l) {
  __builtin_amdgcn_global_load_lds(
      (const __attribute__((address_space(1))) unsigned int*)g,
      (__attribute__((address_space(3))) unsigned int*)l, 16, 0, 0);
}

// ---------------- prep: W_q (f32, D x 496) -> bf16 LDS-image, padded N=512,
// col-major per K-step, XOR-swizzle baked into granule order.
// image[ks][c][slot][e] = Wp[ks*64 + ((slot^(c&7))<<3) + e][c]
__global__ void prep_kernel(const float* __restrict__ Wq,
                            unsigned short* __restrict__ Bimg) {
  int idx = blockIdx.x * 256 + threadIdx.x;  // < 16*512*64 = 524288
  int ks = idx >> 15;
  int rem = idx & 32767;
  int c = rem >> 6;
  int s = (rem >> 3) & 7;
  int e = rem & 7;
  int k8 = s ^ (c & 7);
  int k = ks * 64 + k8 * 8 + e;
  int h = c >> 5, j = c & 31;
  float v = (j < KK) ? Wq[k * HK + h * KK + j] : 0.f;
  Bimg[idx] = f2bf(v);
}

// ---------------- ksum: (B,S,H) = sum over 64 channels per head, f32
__global__ void ksum_kernel(const float* __restrict__ key,
                            float* __restrict__ ksum) {
  const int row = blockIdx.x;   // b*S + s
  const int tid = threadIdx.x;  // 0..255, 4 channels each
  const float4 v = reinterpret_cast<const float4*>(key + (size_t)row * DD)[tid];
  float p = v.x + v.y + v.z + v.w;
  p += __shfl_xor(p, 1);
  p += __shfl_xor(p, 2);
  p += __shfl_xor(p, 4);
  p += __shfl_xor(p, 8);
  if ((tid & 15) == 0) ksum[(size_t)row * HH + (tid >> 4)] = p;
}

// ---------------- fused GEMM (bf16 MFMA) + per-position conv + transpose
// BM=128, BN=512 (16 heads x 32 padded), BK=64, 8 waves (2x4), dbuf LDS 160KB
__global__ __launch_bounds__(512, 2) void mca_kernel(
    const float* __restrict__ q, const float* __restrict__ bq,
    const float* __restrict__ convb, const float* __restrict__ ksum,
    const unsigned short* __restrict__ Bimg, float* __restrict__ out) {
  extern __shared__ char smem[];
  const int tid = threadIdx.x;
  const int wave = tid >> 6, lane = tid & 63;
  const int g = lane >> 4, qq = lane & 15;
  const int wr = wave >> 2, wc = wave & 3;
  const int bid = blockIdx.x;
  const int bb = bid >> 4;
  const int t0 = (bid & 15) << 7;

  char* const bB0 = smem;            // 64KB
  char* const bB1 = smem + 65536;    // 64KB
  char* const bA0 = smem + 131072;   // 16KB
  char* const bA1 = smem + 147456;   // 16KB

  const float* qblk = q + ((size_t)(bb * SS + t0)) * DD;

  f32x4 acc[4][8];
#pragma unroll
  for (int m = 0; m < 4; ++m)
#pragma unroll
    for (int n = 0; n < 8; ++n) acc[m][n] = (f32x4){0.f, 0.f, 0.f, 0.f};

  // per-thread A-staging geometry: 1024 granules (128 rows x 8 slots), 2 per thread
  const int arow0 = tid >> 3;          // rep0 row, rep1 row = arow0+64
  const int aslot = tid & 7;
  const int ak8 = aslot ^ (arow0 & 7); // data granule stored at this slot

  float4 rA[2][2];

  auto stageB = [&](char* dst, int ks) {
    const char* src = (const char*)Bimg + (size_t)ks * 65536 + wave * 1024 + lane * 16;
    char* d = dst + wave * 1024;  // wave-uniform LDS base; HW adds lane*16
#pragma unroll
    for (int rr = 0; rr < 8; ++rr) gll16(src + rr * 8192, d + rr * 8192);
  };

  auto issueA = [&](int ks) {
#pragma unroll
    for (int rep = 0; rep < 2; ++rep) {
      const float* src = qblk + (size_t)(arow0 + rep * 64) * DD + ks * 64 + ak8 * 8;
      rA[rep][0] = ((const float4*)src)[0];
      rA[rep][1] = ((const float4*)src)[1];
    }
  };

  auto writeA = [&](char* dst) {
#pragma unroll
    for (int rep = 0; rep < 2; ++rep) {
      float f[8] = {rA[rep][0].x, rA[rep][0].y, rA[rep][0].z, rA[rep][0].w,
                    rA[rep][1].x, rA[rep][1].y, rA[rep][1].z, rA[rep][1].w};
      unsigned u[4];
#pragma unroll
      for (int i = 0; i < 4; ++i)
        u[i] = (unsigned)f2bf(f[2 * i]) | ((unsigned)f2bf(f[2 * i + 1]) << 16);
      *reinterpret_cast<uint4*>(dst + (arow0 + rep * 64) * 128 + aslot * 16) =
          make_uint4(u[0], u[1], u[2], u[3]);
    }
  };

  auto computeT = [&](const char* bufA, const char* bufB) {
#pragma unroll
    for (int kk = 0; kk < 2; ++kk) {
      const int x = ((kk * 4 + g) ^ (lane & 7)) * 16;  // swizzled 16B slot
      bf16x8 af[4], bf[8];
#pragma unroll
      for (int m = 0; m < 4; ++m)
        af[m] = *reinterpret_cast<const bf16x8*>(bufA + (wr * 64 + m * 16 + qq) * 128 + x);
#pragma unroll
      for (int n = 0; n < 8; ++n)
        bf[n] = *reinterpret_cast<const bf16x8*>(bufB + (wc * 128 + n * 16 + qq) * 128 + x);
#pragma unroll
      for (int m = 0; m < 4; ++m)
#pragma unroll
        for (int n = 0; n < 8; ++n)
          acc[m][n] = __builtin_amdgcn_mfma_f32_16x16x32_bf16(af[m], bf[n], acc[m][n], 0, 0, 0);
    }
  };

  // prologue
  issueA(0);
  stageB(bB0, 0);
  writeA(bA0);
  __syncthreads();

  for (int ks = 0; ks < 16; ++ks) {
    char* cA = (ks & 1) ? bA1 : bA0;
    char* cB = (ks & 1) ? bB1 : bB0;
    char* nA = (ks & 1) ? bA0 : bA1;
    char* nB = (ks & 1) ? bB0 : bB1;
    if (ks < 15) {
      issueA(ks + 1);    // f32 loads issued early (T14)
      stageB(nB, ks + 1);
    }
    computeT(cA, cB);
    if (ks < 15) writeA(nA);  // cvt + ds_write late
    __syncthreads();
  }

  // ---- epilogue: conv over j (K=31) in f32 ----
  float bqv[8];
#pragma unroll
  for (int n = 0; n < 8; ++n) {
    int c = wc * 128 + n * 16 + qq;
    int h = c >> 5, j = c & 31;
    bqv[n] = (j < KK) ? bq[h * KK + j] : 0.f;
  }
  float cb[4];
#pragma unroll
  for (int hp = 0; hp < 4; ++hp) cb[hp] = convb[wc * 4 + hp];

  // stage ksum slice [t0-15, t0+144] x 16 heads into LDS (stride 17 to dodge banks)
  float* kl = reinterpret_cast<float*>(smem);
  for (int i = tid; i < 160 * 16; i += 512) {
    int trow = i >> 4, h = i & 15;
    int t = t0 + trow - 15;
    kl[trow * 17 + h] = (t >= 0 && t < SS) ? ksum[((size_t)bb * SS + t) * HH + h] : 0.f;
  }
  __syncthreads();

#pragma unroll
  for (int m = 0; m < 4; ++m) {
    float part[4][4];
#pragma unroll
    for (int r = 0; r < 4; ++r)
#pragma unroll
      for (int hp = 0; hp < 4; ++hp) part[r][hp] = 0.f;
#pragma unroll
    for (int n = 0; n < 8; ++n) {
      const int hp = n >> 1;
      const int j = (n & 1) * 16 + qq;  // col within head's 32; j==31 has zero weight
      const int h = wc * 4 + hp;
#pragma unroll
      for (int r = 0; r < 4; ++r) {
        const int tl = wr * 64 + m * 16 + g * 4 + r;
        part[r][hp] += (acc[m][n][r] + bqv[n]) * kl[(tl + j) * 17 + h];
      }
    }
#pragma unroll
    for (int r = 0; r < 4; ++r)
#pragma unroll
      for (int hp = 0; hp < 4; ++hp) {
        float v = part[r][hp];
        v += __shfl_xor(v, 1);
        v += __shfl_xor(v, 2);
        v += __shfl_xor(v, 4);
        v += __shfl_xor(v, 8);
        part[r][hp] = v;
      }
    if (qq < 4) {  // lane qq writes row r=qq of this (m, g) for all 4 heads
      const int r = qq;
      const int t = t0 + wr * 64 + m * 16 + g * 4 + r;
#pragma unroll
      for (int hp = 0; hp < 4; ++hp)
        out[((size_t)bb * HH + wc * 4 + hp) * SS + t] = part[r][hp] + cb[hp];
    }
  }
}

extern "C" void kernel_launch(void* const* d_in, const int* in_sizes, int n_in,
                              void* d_out, int out_size, void* d_ws, size_t ws_size,
                              hipStream_t stream) {
  const float* q   = (const float*)d_in[0];
  const float* key = (const float*)d_in[1];
  // d_in[2] (values) and d_in[3] (lengths) are unused by the reference
  const float* Wq  = (const float*)d_in[4];
  const float* bq  = (const float*)d_in[5];
  const float* cvb = (const float*)d_in[6];
  float* out = (float*)d_out;

  float* ksum = (float*)d_ws;                                        // 2 MB f32
  unsigned short* Bimg = (unsigned short*)((char*)d_ws + 2097152);   // 1 MB bf16

  hipFuncSetAttribute((const void*)mca_kernel,
                      hipFuncAttributeMaxDynamicSharedMemorySize, 163840);

  prep_kernel<<<2048, 256, 0, stream>>>(Wq, Bimg);
  ksum_kernel<<<BB * SS, 256, 0, stream>>>(key, ksum);
  mca_kernel<<<BB * (SS / 128), 512, 163840, stream>>>(q, bq, cvb, ksum, Bimg, out);
}